// Round 2
// baseline (210.437 us; speedup 1.0000x reference)
//
#include <hip/hip_runtime.h>

#define BLOCK 256

typedef int   v4i __attribute__((ext_vector_type(4)));
typedef float v4f __attribute__((ext_vector_type(4)));

// per-profile targets (5 entries) and config multipliers (4 entries)
__device__ __constant__ float c_target_delay[5] = {2.0f, 1.0f, 0.5f, 5.0f, 3.0f};
__device__ __constant__ float c_target_pad[5]   = {0.08f, 0.12f, 0.05f, 0.15f, 0.10f};
__device__ __constant__ float c_config_mult[4]  = {1.0f, 1.3f, 1.6f, 2.0f};

// One block per row; fused final reduction via deterministic last-block ticket.
__global__ __launch_bounds__(BLOCK) void fused_loss_kernel(
    const int*   __restrict__ sizes,      // [B,S] int32
    const float* __restrict__ delays,     // [B,S] f32
    const int*   __restrict__ dirs,       // [B,S] int32
    const float* __restrict__ delay_ms,   // [B]
    const float* __restrict__ pad_norm,   // [B]
    const float* __restrict__ conf,       // [B]
    const int*   __restrict__ pids,       // [B]
    float*       __restrict__ row_out,    // [B] scratch (d_ws)
    unsigned*    __restrict__ ticket,     // 1 counter (d_ws), pre-zeroed
    float*       __restrict__ out,        // [1]
    int S, int B, float invB)
{
    const int r    = blockIdx.x;
    const int tid  = threadIdx.x;
    const int lane = tid & 63;
    const int wv   = tid >> 6;
    const int base = tid * 8;               // S == BLOCK*8
    const long long rowoff = (long long)r * (long long)S;

    const int*   srow = sizes  + rowoff;
    const float* drow = delays + rowoff;
    const int*   grow = dirs   + rowoff;

    const float pad = pad_norm[r];
    const float dly = delay_ms[r];

    // Streamed, read-once: non-temporal 16B loads (2 per array per thread).
    v4i s0 = __builtin_nontemporal_load((const v4i*)(srow + base));
    v4i s1 = __builtin_nontemporal_load((const v4i*)(srow + base) + 1);
    v4f d0 = __builtin_nontemporal_load((const v4f*)(drow + base));
    v4f d1 = __builtin_nontemporal_load((const v4f*)(drow + base) + 1);
    v4i g0 = __builtin_nontemporal_load((const v4i*)(grow + base));
    v4i g1 = __builtin_nontemporal_load((const v4i*)(grow + base) + 1);

    float sz[8] = {(float)s0[0], (float)s0[1], (float)s0[2], (float)s0[3],
                   (float)s1[0], (float)s1[1], (float)s1[2], (float)s1[3]};
    float dl[8] = {d0[0], d0[1], d0[2], d0[3], d1[0], d1[1], d1[2], d1[3]};
    float dr[8] = {(float)g0[0], (float)g0[1], (float)g0[2], (float)g0[3],
                   (float)g1[0], (float)g1[1], (float)g1[2], (float)g1[3]};

    // prev element of this thread's chunk = previous thread's last raw element
    const float rawsz7 = sz[7], rawdr7 = dr[7];
    float psz = __shfl_up(rawsz7, 1, 64);
    float pdr = __shfl_up(rawdr7, 1, 64);

    __shared__ float wl_sz[BLOCK / 64], wl_dr[BLOCK / 64];
    if (lane == 63) { wl_sz[wv] = rawsz7; wl_dr[wv] = rawdr7; }
    __syncthreads();
    if (lane == 0) {
        if (tid == 0) { psz = -1.0f; pdr = -1.0f; }
        else          { psz = wl_sz[wv - 1]; pdr = wl_dr[wv - 1]; }
    }

    // last-packet morphing (the morphed value is never used as a "prev")
    if (base + 8 == S) {
        sz[7] = fminf(sz[7] + pad * 1500.0f, 1500.0f);
        dl[7] = dl[7] + dly;
    }

    float sum = 0.0f;
    #pragma unroll
    for (int j = 0; j < 8; ++j) {
        float inc = 0.0f;
        inc += (sz[j] > 1400.0f)           ? 0.6f : 0.0f;
        inc += (dl[j] < 0.05f)             ? 0.4f : 0.0f;
        inc += (fabsf(sz[j] - psz) < 0.5f) ? 0.2f : 0.0f;
        inc += (dr[j] != pdr)              ? 0.1f : 0.0f;
        sum += inc;
        psz = sz[j];
        pdr = dr[j];
    }

    // wave reduce, then cross-wave via LDS
    #pragma unroll
    for (int off = 32; off > 0; off >>= 1)
        sum += __shfl_down(sum, off, 64);

    __shared__ float wsum[BLOCK / 64];
    if (lane == 0) wsum[wv] = sum;
    __syncthreads();

    __shared__ unsigned s_isLast;
    if (tid == 0) {
        float tot = 0.0f;
        #pragma unroll
        for (int w = 0; w < BLOCK / 64; ++w) tot += wsum[w];

        const int pid = pids[r];
        const float mult  = c_config_mult[pid & 3];
        const float score = tot * (100.0f / (float)S) * mult;

        float v = 0.0f;
        v += (2.0f / 30.0f) * fmaxf(score - 15.0f, 0.0f);                 // DPI
        v += 0.5f * (fabsf(dly - c_target_delay[pid]) +
                     fabsf(pad - c_target_pad[pid]));                      // similarity
        v += (0.3f / 20.0f) * fmaxf(dly - 20.0f, 0.0f);                   // efficiency (delay)
        v += 0.3f * fmaxf(pad - 0.3f, 0.0f);                              // efficiency (pad)
        const float ev = (score < 30.0f) ? 1.0f : 0.0f;
        const float c  = conf[r] - ev;
        v += 0.2f * c * c;                                                 // confidence

        row_out[r] = v * invB;
        __threadfence();                       // release: make row_out visible device-wide
        unsigned prev = atomicAdd(ticket, 1u); // device-scope
        s_isLast = (prev == (unsigned)(gridDim.x - 1)) ? 1u : 0u;
    }
    __syncthreads();

    if (s_isLast) {
        __threadfence();                       // acquire: see all rows' stores
        float s = 0.0f;
        for (int i = tid; i < B; i += BLOCK) s += row_out[i];

        #pragma unroll
        for (int off = 32; off > 0; off >>= 1)
            s += __shfl_down(s, off, 64);

        __syncthreads();                        // wsum reuse safe (tid0 done reading)
        if (lane == 0) wsum[wv] = s;
        __syncthreads();
        if (tid == 0) {
            float tot = 0.0f;
            #pragma unroll
            for (int w = 0; w < BLOCK / 64; ++w) tot += wsum[w];
            out[0] = tot;
        }
    }
}

extern "C" void kernel_launch(void* const* d_in, const int* in_sizes, int n_in,
                              void* d_out, int out_size, void* d_ws, size_t ws_size,
                              hipStream_t stream) {
    const int*   sizes    = (const int*)  d_in[0];
    const float* delays   = (const float*)d_in[1];
    const int*   dirs     = (const int*)  d_in[2];
    const float* delay_ms = (const float*)d_in[3];
    const float* pad_norm = (const float*)d_in[4];
    const float* conf     = (const float*)d_in[5];
    const int*   pids     = (const int*)  d_in[6];
    float* out = (float*)d_out;

    const int B = in_sizes[3];                 // 4096
    const int S = in_sizes[0] / B;             // 2048

    float*    row_ws = (float*)d_ws;                               // B floats
    unsigned* ticket = (unsigned*)((char*)d_ws + (size_t)B * 4);   // 1 uint

    hipMemsetAsync(ticket, 0, sizeof(unsigned), stream);           // graph-capturable

    fused_loss_kernel<<<B, BLOCK, 0, stream>>>(
        sizes, delays, dirs, delay_ms, pad_norm, conf, pids,
        row_ws, ticket, out, S, B, 1.0f / (float)B);
}

// Round 3
// 26.202 us; speedup vs baseline: 8.0313x; 8.0313x over previous
//
#include <hip/hip_runtime.h>

#define BLOCK 256

// per-profile targets (5 entries) and config multipliers (4 entries)
__device__ __constant__ float c_target_delay[5] = {2.0f, 1.0f, 0.5f, 5.0f, 3.0f};
__device__ __constant__ float c_target_pad[5]   = {0.08f, 0.12f, 0.05f, 0.15f, 0.10f};
__device__ __constant__ float c_config_mult[4]  = {1.0f, 1.3f, 1.6f, 2.0f};

// One block per row. Each thread handles 8 contiguous elements.
// prev-element handoff via shuffles (no stray scalar global loads).
__global__ __launch_bounds__(BLOCK) void row_loss_kernel(
    const int*   __restrict__ sizes,      // [B,S] int32
    const float* __restrict__ delays,     // [B,S] f32
    const int*   __restrict__ dirs,       // [B,S] int32
    const float* __restrict__ delay_ms,   // [B]
    const float* __restrict__ pad_norm,   // [B]
    const float* __restrict__ conf,       // [B]
    const int*   __restrict__ pids,       // [B]
    float*       __restrict__ row_out,    // [B] per-row contribution to total
    int S, float invB)
{
    const int r    = blockIdx.x;
    const int tid  = threadIdx.x;
    const int lane = tid & 63;
    const int wv   = tid >> 6;
    const int base = tid * 8;               // S == BLOCK*8 == 2048
    const long long rowoff = (long long)r * (long long)S;

    const int*   srow = sizes  + rowoff;
    const float* drow = delays + rowoff;
    const int*   grow = dirs   + rowoff;

    const float pad = pad_norm[r];
    const float dly = delay_ms[r];

    // Plain coalesced 16B vector loads (2 per array per thread).
    const int4*   sv = (const int4*)(srow + base);
    const float4* dv = (const float4*)(drow + base);
    const int4*   gv = (const int4*)(grow + base);
    int4   s0 = sv[0], s1 = sv[1];
    float4 d0 = dv[0], d1 = dv[1];
    int4   g0 = gv[0], g1 = gv[1];

    float sz[8] = {(float)s0.x, (float)s0.y, (float)s0.z, (float)s0.w,
                   (float)s1.x, (float)s1.y, (float)s1.z, (float)s1.w};
    float dl[8] = {d0.x, d0.y, d0.z, d0.w, d1.x, d1.y, d1.z, d1.w};
    float dr[8] = {(float)g0.x, (float)g0.y, (float)g0.z, (float)g0.w,
                   (float)g1.x, (float)g1.y, (float)g1.z, (float)g1.w};

    // prev element of this thread's chunk = previous thread's last raw element
    const float rawsz7 = sz[7], rawdr7 = dr[7];
    float psz = __shfl_up(rawsz7, 1, 64);
    float pdr = __shfl_up(rawdr7, 1, 64);

    __shared__ float wl_sz[BLOCK / 64], wl_dr[BLOCK / 64];
    if (lane == 63) { wl_sz[wv] = rawsz7; wl_dr[wv] = rawdr7; }
    __syncthreads();
    if (lane == 0) {
        if (tid == 0) { psz = -1.0f; pdr = -1.0f; }
        else          { psz = wl_sz[wv - 1]; pdr = wl_dr[wv - 1]; }
    }

    // last-packet morphing (morphed value is never used as a "prev":
    // reference computes prev from sizes_f[:, :-1])
    if (base + 8 == S) {
        sz[7] = fminf(sz[7] + pad * 1500.0f, 1500.0f);
        dl[7] = dl[7] + dly;
    }

    float sum = 0.0f;
    #pragma unroll
    for (int j = 0; j < 8; ++j) {
        float inc = 0.0f;
        inc += (sz[j] > 1400.0f)           ? 0.6f : 0.0f;
        inc += (dl[j] < 0.05f)             ? 0.4f : 0.0f;
        inc += (fabsf(sz[j] - psz) < 0.5f) ? 0.2f : 0.0f;
        inc += (dr[j] != pdr)              ? 0.1f : 0.0f;
        sum += inc;
        psz = sz[j];
        pdr = dr[j];
    }

    // wave (64-lane) reduce, then cross-wave via LDS
    #pragma unroll
    for (int off = 32; off > 0; off >>= 1)
        sum += __shfl_down(sum, off, 64);

    __shared__ float wsum[BLOCK / 64];
    if (lane == 0) wsum[wv] = sum;
    __syncthreads();

    if (tid == 0) {
        float tot = 0.0f;
        #pragma unroll
        for (int w = 0; w < BLOCK / 64; ++w) tot += wsum[w];

        const int pid = pids[r];
        const float mult  = c_config_mult[pid & 3];
        const float score = tot * (100.0f / (float)S) * mult;

        float v = 0.0f;
        v += (2.0f / 30.0f) * fmaxf(score - 15.0f, 0.0f);                 // DPI
        v += 0.5f * (fabsf(dly - c_target_delay[pid]) +
                     fabsf(pad - c_target_pad[pid]));                      // similarity
        v += (0.3f / 20.0f) * fmaxf(dly - 20.0f, 0.0f);                   // efficiency (delay)
        v += 0.3f * fmaxf(pad - 0.3f, 0.0f);                              // efficiency (pad)
        const float ev = (score < 30.0f) ? 1.0f : 0.0f;
        const float c  = conf[r] - ev;
        v += 0.2f * c * c;                                                 // confidence

        row_out[r] = v * invB;
    }
}

__global__ __launch_bounds__(BLOCK) void reduce_kernel(
    const float* __restrict__ row, float* __restrict__ out, int B)
{
    const int tid = threadIdx.x;
    float s = 0.0f;
    for (int i = tid; i < B; i += BLOCK) s += row[i];

    #pragma unroll
    for (int off = 32; off > 0; off >>= 1)
        s += __shfl_down(s, off, 64);

    __shared__ float wsum[BLOCK / 64];
    if ((tid & 63) == 0) wsum[tid >> 6] = s;
    __syncthreads();

    if (tid == 0) {
        float tot = 0.0f;
        #pragma unroll
        for (int w = 0; w < BLOCK / 64; ++w) tot += wsum[w];
        out[0] = tot;
    }
}

extern "C" void kernel_launch(void* const* d_in, const int* in_sizes, int n_in,
                              void* d_out, int out_size, void* d_ws, size_t ws_size,
                              hipStream_t stream) {
    const int*   sizes    = (const int*)  d_in[0];
    const float* delays   = (const float*)d_in[1];
    const int*   dirs     = (const int*)  d_in[2];
    const float* delay_ms = (const float*)d_in[3];
    const float* pad_norm = (const float*)d_in[4];
    const float* conf     = (const float*)d_in[5];
    const int*   pids     = (const int*)  d_in[6];
    float* out = (float*)d_out;

    const int B = in_sizes[3];                 // 4096
    const int S = in_sizes[0] / B;             // 2048

    float* row_ws = (float*)d_ws;              // B floats of scratch

    row_loss_kernel<<<B, BLOCK, 0, stream>>>(
        sizes, delays, dirs, delay_ms, pad_norm, conf, pids,
        row_ws, S, 1.0f / (float)B);

    reduce_kernel<<<1, BLOCK, 0, stream>>>(row_ws, out, B);
}

// Round 4
// 24.706 us; speedup vs baseline: 8.5176x; 1.0605x over previous
//
#include <hip/hip_runtime.h>

#define BLOCK 256

// per-profile targets (5 entries) and config multipliers (4 entries)
__device__ __constant__ float c_target_delay[5] = {2.0f, 1.0f, 0.5f, 5.0f, 3.0f};
__device__ __constant__ float c_target_pad[5]   = {0.08f, 0.12f, 0.05f, 0.15f, 0.10f};
__device__ __constant__ float c_config_mult[4]  = {1.0f, 1.3f, 1.6f, 2.0f};

// One block per row, but each of the 4 waves independently owns a 512-elem
// segment: no LDS, no __syncthreads, no block-level epilogue. Lane 0 of each
// wave writes one partial sum. All per-row score math moves to kernel 2.
__global__ __launch_bounds__(BLOCK) void seg_kernel(
    const int*   __restrict__ sizes,      // [B,S] int32
    const float* __restrict__ delays,     // [B,S] f32
    const int*   __restrict__ dirs,       // [B,S] int32
    const float* __restrict__ delay_ms,   // [B]
    const float* __restrict__ pad_norm,   // [B]
    float*       __restrict__ partial,    // [B*4] per-segment inc sums
    int S)
{
    const int lane = threadIdx.x & 63;
    const int seg  = threadIdx.x >> 6;          // 0..3
    const int row  = blockIdx.x;
    const long long rowoff = (long long)row * (long long)S;
    const int segbase = seg * 512;              // S == 4*512
    const int base = segbase + lane * 8;

    const int*   srow = sizes  + rowoff;
    const float* drow = delays + rowoff;
    const int*   grow = dirs   + rowoff;

    // 6 coalesced 16B loads per thread
    int4   s0 = ((const int4*)(srow + base))[0];
    int4   s1 = ((const int4*)(srow + base))[1];
    float4 d0 = ((const float4*)(drow + base))[0];
    float4 d1 = ((const float4*)(drow + base))[1];
    int4   g0 = ((const int4*)(grow + base))[0];
    int4   g1 = ((const int4*)(grow + base))[1];

    float sz[8] = {(float)s0.x, (float)s0.y, (float)s0.z, (float)s0.w,
                   (float)s1.x, (float)s1.y, (float)s1.z, (float)s1.w};
    float dl[8] = {d0.x, d0.y, d0.z, d0.w, d1.x, d1.y, d1.z, d1.w};
    float dr[8] = {(float)g0.x, (float)g0.y, (float)g0.z, (float)g0.w,
                   (float)g1.x, (float)g1.y, (float)g1.z, (float)g1.w};

    // prev element of this thread's chunk: previous lane's last raw element;
    // lane 0 takes the segment-boundary element (cache hit) or the sentinel.
    float psz = __shfl_up(sz[7], 1, 64);
    float pdr = __shfl_up(dr[7], 1, 64);
    if (lane == 0) {
        if (seg == 0) { psz = -1.0f; pdr = -1.0f; }
        else {
            psz = (float)srow[segbase - 1];
            pdr = (float)grow[segbase - 1];
        }
    }

    // last-packet morphing: only the very last element of the row
    // (morphed value is never used as a "prev" — reference shifts pre-morph cols)
    if (seg == 3 && lane == 63) {
        sz[7] = fminf(sz[7] + pad_norm[row] * 1500.0f, 1500.0f);
        dl[7] = dl[7] + delay_ms[row];
    }

    float sum = 0.0f;
    #pragma unroll
    for (int j = 0; j < 8; ++j) {
        float inc = 0.0f;
        inc += (sz[j] > 1400.0f)           ? 0.6f : 0.0f;
        inc += (dl[j] < 0.05f)             ? 0.4f : 0.0f;
        inc += (fabsf(sz[j] - psz) < 0.5f) ? 0.2f : 0.0f;
        inc += (dr[j] != pdr)              ? 0.1f : 0.0f;
        sum += inc;
        psz = sz[j];
        pdr = dr[j];
    }

    // wave-local reduce; no cross-wave communication at all
    #pragma unroll
    for (int off = 32; off > 0; off >>= 1)
        sum += __shfl_down(sum, off, 64);

    if (lane == 0) partial[row * 4 + seg] = sum;
}

// Single block: fold 4 partials per row, apply per-row score math, reduce.
__global__ __launch_bounds__(1024) void final_kernel(
    const float* __restrict__ partial,    // [B*4]
    const float* __restrict__ delay_ms,   // [B]
    const float* __restrict__ pad_norm,   // [B]
    const float* __restrict__ conf,       // [B]
    const int*   __restrict__ pids,       // [B]
    float*       __restrict__ out,        // [1]
    int B, float inv_s_x100, float invB)
{
    const int tid = threadIdx.x;
    float s = 0.0f;

    for (int r = tid; r < B; r += 1024) {
        float4 p = ((const float4*)partial)[r];
        const float tot = (p.x + p.y) + (p.z + p.w);

        const int   pid = pids[r];
        const float dly = delay_ms[r];
        const float pad = pad_norm[r];
        const float score = tot * inv_s_x100 * c_config_mult[pid & 3];

        float v = 0.0f;
        v += (2.0f / 30.0f) * fmaxf(score - 15.0f, 0.0f);                 // DPI
        v += 0.5f * (fabsf(dly - c_target_delay[pid]) +
                     fabsf(pad - c_target_pad[pid]));                      // similarity
        v += (0.3f / 20.0f) * fmaxf(dly - 20.0f, 0.0f);                   // efficiency (delay)
        v += 0.3f * fmaxf(pad - 0.3f, 0.0f);                              // efficiency (pad)
        const float ev = (score < 30.0f) ? 1.0f : 0.0f;
        const float c  = conf[r] - ev;
        v += 0.2f * c * c;                                                 // confidence

        s += v * invB;
    }

    #pragma unroll
    for (int off = 32; off > 0; off >>= 1)
        s += __shfl_down(s, off, 64);

    __shared__ float wsum[1024 / 64];
    if ((tid & 63) == 0) wsum[tid >> 6] = s;
    __syncthreads();

    if (tid == 0) {
        float tot = 0.0f;
        #pragma unroll
        for (int w = 0; w < 1024 / 64; ++w) tot += wsum[w];
        out[0] = tot;
    }
}

extern "C" void kernel_launch(void* const* d_in, const int* in_sizes, int n_in,
                              void* d_out, int out_size, void* d_ws, size_t ws_size,
                              hipStream_t stream) {
    const int*   sizes    = (const int*)  d_in[0];
    const float* delays   = (const float*)d_in[1];
    const int*   dirs     = (const int*)  d_in[2];
    const float* delay_ms = (const float*)d_in[3];
    const float* pad_norm = (const float*)d_in[4];
    const float* conf     = (const float*)d_in[5];
    const int*   pids     = (const int*)  d_in[6];
    float* out = (float*)d_out;

    const int B = in_sizes[3];                 // 4096
    const int S = in_sizes[0] / B;             // 2048

    float* partial = (float*)d_ws;             // B*4 floats of scratch

    seg_kernel<<<B, BLOCK, 0, stream>>>(
        sizes, delays, dirs, delay_ms, pad_norm, partial, S);

    final_kernel<<<1, 1024, 0, stream>>>(
        partial, delay_ms, pad_norm, conf, pids, out,
        B, 100.0f / (float)S, 1.0f / (float)B);
}